// Round 5
// baseline (202.952 us; speedup 1.0000x reference)
//
#include <hip/hip_runtime.h>
#include <math.h>

#define N_NODES 100000
#define N_EDGES 800000
#define DIM_IN 128
#define DIM_OUT 256
#define NPB 128   // nodes per block in the MFMA GEMM (2 sub-tiles of 64)

typedef __bf16 bf16x8 __attribute__((ext_vector_type(8)));
typedef float  f32x4  __attribute__((ext_vector_type(4)));

// ---------------- prep: convert W to bf16 + zero counts --------------------
__global__ __launch_bounds__(256) void k_prep(const float* __restrict__ W,
                                              unsigned short* __restrict__ Wb,
                                              int* __restrict__ counts) {
    int i = blockIdx.x * 256 + threadIdx.x;
    if (i < DIM_IN * DIM_OUT) Wb[i] = __builtin_bit_cast(unsigned short, (__bf16)W[i]);
    int j = i - DIM_IN * DIM_OUT;
    if (j >= 0 && j < N_NODES) counts[j] = 0;
}

// ---------------- CSR build ------------------------------------------------
__global__ __launch_bounds__(256) void k_count(const int* __restrict__ dst,
                                               int* __restrict__ counts) {
    int e = blockIdx.x * 256 + threadIdx.x;   // grid exact: 800000/256
    atomicAdd(&counts[dst[e]], 1);
}

// 1024-thread block scan using wave shuffles (2 barriers instead of 20).
__global__ __launch_bounds__(1024) void k_scan1(const int* __restrict__ counts,
                                                int* __restrict__ incl,
                                                int* __restrict__ bsum) {
    __shared__ int ws[16];
    int tid = threadIdx.x, lane = tid & 63, wid = tid >> 6;
    int i = blockIdx.x * 1024 + tid;
    int v = (i < N_NODES) ? counts[i] : 0;
#pragma unroll
    for (int d = 1; d < 64; d <<= 1) {
        int t = __shfl_up(v, d, 64);
        if (lane >= d) v += t;
    }
    if (lane == 63) ws[wid] = v;
    __syncthreads();
    if (wid == 0) {
        int s = (lane < 16) ? ws[lane] : 0;
#pragma unroll
        for (int d = 1; d < 16; d <<= 1) {
            int t = __shfl_up(s, d, 64);
            if (lane >= d) s += t;
        }
        if (lane < 16) ws[lane] = s;
    }
    __syncthreads();
    if (wid > 0) v += ws[wid - 1];
    if (i < N_NODES) incl[i] = v;
    if (tid == 1023) bsum[blockIdx.x] = v;
}

__global__ __launch_bounds__(128) void k_scan2(const int* __restrict__ bsum,
                                               int* __restrict__ boff) {
    __shared__ int s[128];
    int tid = threadIdx.x;
    int v = (tid < 98) ? bsum[tid] : 0;
    s[tid] = v;
    __syncthreads();
    for (int off = 1; off < 128; off <<= 1) {
        int t = (tid >= off) ? s[tid - off] : 0;
        __syncthreads();
        s[tid] += t;
        __syncthreads();
    }
    if (tid < 98) boff[tid] = s[tid];
}

__global__ __launch_bounds__(1024) void k_scan3(const int* __restrict__ counts,
                                                int* __restrict__ incl,
                                                const int* __restrict__ boff,
                                                int* __restrict__ cursor) {
    int i = blockIdx.x * 1024 + threadIdx.x;
    if (i < N_NODES) {
        int base = (blockIdx.x > 0) ? boff[blockIdx.x - 1] : 0;
        int v = incl[i] + base;
        incl[i] = v;                 // global inclusive scan
        cursor[i] = v - counts[i];   // row start (exclusive)
    }
}

__global__ __launch_bounds__(256) void k_fill(const int* __restrict__ src,
                                              const int* __restrict__ dst,
                                              int* __restrict__ cursor,
                                              int* __restrict__ csr) {
    int e = blockIdx.x * 256 + threadIdx.x;
    int pos = atomicAdd(&cursor[dst[e]], 1);
    csr[pos] = src[e];
}

// ---------------- Aggregate: mb[n] = bf16(deg_inv[n] * sum x[src]) ---------
// One wave per node; lane holds float2 of the 128-dim row; unroll x4 with
// two accumulator chains for load ILP.
__global__ __launch_bounds__(256) void k_agg(const float* __restrict__ x,
                                             const int* __restrict__ csr,
                                             const int* __restrict__ incl,
                                             const int* __restrict__ counts,
                                             const float* __restrict__ deg_inv,
                                             unsigned short* __restrict__ mb) {
    int wave = threadIdx.x >> 6;
    int lane = threadIdx.x & 63;
    int node = blockIdx.x * 4 + wave;        // grid exact: 25000*4
    int end = __builtin_amdgcn_readfirstlane(incl[node]);
    int beg = end - __builtin_amdgcn_readfirstlane(counts[node]);
    float a0 = 0.f, a1 = 0.f, b0 = 0.f, b1 = 0.f;
    int e = beg;
    for (; e + 3 < end; e += 4) {
        int s0 = csr[e], s1 = csr[e + 1], s2 = csr[e + 2], s3 = csr[e + 3];
        float2 v0 = *reinterpret_cast<const float2*>(x + (size_t)s0 * DIM_IN + lane * 2);
        float2 v1 = *reinterpret_cast<const float2*>(x + (size_t)s1 * DIM_IN + lane * 2);
        float2 v2 = *reinterpret_cast<const float2*>(x + (size_t)s2 * DIM_IN + lane * 2);
        float2 v3 = *reinterpret_cast<const float2*>(x + (size_t)s3 * DIM_IN + lane * 2);
        a0 += v0.x; a1 += v0.y;
        b0 += v1.x; b1 += v1.y;
        a0 += v2.x; a1 += v2.y;
        b0 += v3.x; b1 += v3.y;
    }
    for (; e < end; ++e) {
        int s0 = csr[e];
        float2 v0 = *reinterpret_cast<const float2*>(x + (size_t)s0 * DIM_IN + lane * 2);
        a0 += v0.x; a1 += v0.y;
    }
    float d = deg_inv[node];
    float r0 = (a0 + b0) * d;
    float r1 = (a1 + b1) * d;
    unsigned short q0 = __builtin_bit_cast(unsigned short, (__bf16)r0);
    unsigned short q1 = __builtin_bit_cast(unsigned short, (__bf16)r1);
    reinterpret_cast<unsigned*>(mb + (size_t)node * DIM_IN)[lane] =
        (unsigned)q0 | ((unsigned)q1 << 16);
}

// ---------------- GELU (tanh form, branch-free) ----------------------------
__device__ __forceinline__ float gelu_f(float h) {
    float u = h * h;
    float inner = h * (0.7978845608f + 0.0356774081f * u);
    float a = __builtin_amdgcn_exp2f(-2.8853900818f * __builtin_fabsf(inner));
    float t = (1.f - a) * __builtin_amdgcn_rcpf(1.f + a);
    t = __builtin_copysignf(t, inner);
    return 0.5f * h * (1.f + t);
}

// ---------------- MFMA GEMM + bias + GELU (swapped operands) ---------------
// mfma(A=W_frag, B=m_frag): D[row=out, col=node]. Lane (kg,lr):
//   A row = lr -> out = o0+mt*16+lr, k = ks*32+kg*8   (16B from Wb row)
//   B col = lr -> node = n0+nt*16+lr, k = ks*32+kg*8  (16B from mb row)
//   D: col = lane&15 = node, row = kg*4+r = out-within-16
// => lane's f32x4 = 4 consecutive out channels of ONE node -> float4 store.
__global__ __launch_bounds__(256) void k_gemm(
    const unsigned short* __restrict__ mb,
    const unsigned short* __restrict__ Wb,
    const float* __restrict__ bias,
    float* __restrict__ out)
{
    const int wave = threadIdx.x >> 6;
    const int lane = threadIdx.x & 63;
    const int lr = lane & 15;
    const int kg = lane >> 4;
    const int o0 = wave * 64;
    const int n_base = blockIdx.x * NPB;

    bf16x8 wfr[4][4];
#pragma unroll
    for (int mt = 0; mt < 4; ++mt)
#pragma unroll
        for (int ks = 0; ks < 4; ++ks)
            wfr[mt][ks] = *reinterpret_cast<const bf16x8*>(
                Wb + (size_t)(o0 + mt * 16 + lr) * DIM_IN + ks * 32 + kg * 8);

    f32x4 bias4[4];
#pragma unroll
    for (int mt = 0; mt < 4; ++mt)
        bias4[mt] = *reinterpret_cast<const f32x4*>(bias + o0 + mt * 16 + kg * 4);

#pragma unroll
    for (int st = 0; st < NPB / 64; ++st) {
        const int n0 = n_base + st * 64;
        if (n0 >= N_NODES) break;

        bf16x8 mfr[4][4];
#pragma unroll
        for (int nt = 0; nt < 4; ++nt) {
            int node = n0 + nt * 16 + lr;
            node = node < N_NODES ? node : N_NODES - 1;
            const unsigned short* brow = mb + (size_t)node * DIM_IN;
#pragma unroll
            for (int ks = 0; ks < 4; ++ks)
                mfr[nt][ks] = *reinterpret_cast<const bf16x8*>(brow + ks * 32 + kg * 8);
        }

        f32x4 acc[4][4] = {};
#pragma unroll
        for (int ks = 0; ks < 4; ++ks)
#pragma unroll
            for (int mt = 0; mt < 4; ++mt)
#pragma unroll
                for (int nt = 0; nt < 4; ++nt)
                    acc[mt][nt] = __builtin_amdgcn_mfma_f32_16x16x32_bf16(
                        wfr[mt][ks], mfr[nt][ks], acc[mt][nt], 0, 0, 0);

#pragma unroll
        for (int nt = 0; nt < 4; ++nt) {
            int node = n0 + nt * 16 + lr;
            if (node < N_NODES) {
                float* orow = out + (size_t)node * DIM_OUT + o0 + kg * 4;
#pragma unroll
                for (int mt = 0; mt < 4; ++mt) {
                    f32x4 h = acc[mt][nt] + bias4[mt];
                    f32x4 g;
                    g[0] = gelu_f(h[0]);
                    g[1] = gelu_f(h[1]);
                    g[2] = gelu_f(h[2]);
                    g[3] = gelu_f(h[3]);
                    __builtin_nontemporal_store(g, reinterpret_cast<f32x4*>(orow + mt * 16));
                }
            }
        }
    }
}

extern "C" void kernel_launch(void* const* d_in, const int* in_sizes, int n_in,
                              void* d_out, int out_size, void* d_ws, size_t ws_size,
                              hipStream_t stream) {
    const float* x       = (const float*)d_in[0];
    const int*   ei      = (const int*)d_in[1];
    const float* deg_inv = (const float*)d_in[2];
    const float* W       = (const float*)d_in[3];
    const float* bias    = (const float*)d_in[4];
    float*       out     = (float*)d_out;

    const int* src = ei;
    const int* dst = ei + N_EDGES;

    // ws layout: mb | counts | incl | cursor | bsum | boff | csr | Wb
    unsigned short* mb = (unsigned short*)d_ws;
    size_t mb_bytes = (size_t)N_NODES * DIM_IN * sizeof(unsigned short);   // 25.6 MB
    int* counts = (int*)((char*)d_ws + mb_bytes);
    int* incl   = counts + N_NODES;
    int* cursor = incl + N_NODES;
    int* bsum   = cursor + N_NODES;
    int* boff   = bsum + 128;
    int* csr    = boff + 128;
    unsigned short* Wb = (unsigned short*)(csr + N_EDGES);

    k_prep <<<(DIM_IN * DIM_OUT + N_NODES + 255) / 256, 256, 0, stream>>>(W, Wb, counts);
    k_count<<<N_EDGES / 256, 256, 0, stream>>>(dst, counts);
    k_scan1<<<(N_NODES + 1023) / 1024, 1024, 0, stream>>>(counts, incl, bsum);
    k_scan2<<<1, 128, 0, stream>>>(bsum, boff);
    k_scan3<<<(N_NODES + 1023) / 1024, 1024, 0, stream>>>(counts, incl, boff, cursor);
    k_fill <<<N_EDGES / 256, 256, 0, stream>>>(src, dst, cursor, csr);
    k_agg  <<<N_NODES / 4, 256, 0, stream>>>(x, csr, incl, counts, deg_inv, mb);
    k_gemm <<<(N_NODES + NPB - 1) / NPB, 256, 0, stream>>>(mb, Wb, bias, out);
}